// Round 6
// baseline (256.566 us; speedup 1.0000x reference)
//
#include <hip/hip_runtime.h>
#include <hip/hip_bf16.h>

#define N_TOKENS 16384
#define DIM      2048
#define NEXP     64
#define TOPK     8
#define LOSCALE  2048.0f      // 2^11, exact power of two
#define NBLOCKS  512          // 32 tokens per block
#define TOKPB    32
#define LSTRIDE  66           // exchange stride: <=2-way bank aliasing
#define NREP     32           // replicated aux accumulators
#define NROUNDS  16           // K rounds of 128 floats
#define NBUF     3            // triple-buffered A stage
#define BUFSZ    (TOKPB * 128)   // floats per stage buffer (16 KB)

typedef _Float16 half8   __attribute__((ext_vector_type(8)));
typedef float    floatx4 __attribute__((ext_vector_type(4)));

// ---------------------------------------------------------------------------
// Kernel 0: split W (64x2048 fp32) into f16 hi/lo planes.
// ---------------------------------------------------------------------------
__global__ __launch_bounds__(256) void wprep_kernel(const float* __restrict__ W,
                                                    _Float16* __restrict__ Whi,
                                                    _Float16* __restrict__ Wlo) {
    int i = blockIdx.x * 256 + threadIdx.x;
    float w = W[i];
    _Float16 h = (_Float16)w;
    Whi[i] = h;
    Wlo[i] = (_Float16)((w - (float)h) * LOSCALE);
}

// async 16B global->LDS (DMA writes lds_base + lane*16, linear)
__device__ __forceinline__ void gl_lds16(const float* src, float* lds_base, int byteoff) {
    __builtin_amdgcn_global_load_lds(
        (const __attribute__((address_space(1))) unsigned int*)src,
        (__attribute__((address_space(3))) unsigned int*)((char*)lds_base + byteoff),
        16, 0, 0);
}

// split 8 f32 -> f16 hi/lo half8 pair (hi = rn(f32), lo = (f32-hi)*2^11)
__device__ __forceinline__ void split8(const floatx4& f0, const floatx4& f1,
                                       half8& H, half8& L) {
    #pragma unroll
    for (int j = 0; j < 4; ++j) {
        _Float16 h = (_Float16)f0[j];
        H[j] = h; L[j] = (_Float16)((f0[j] - (float)h) * LOSCALE);
    }
    #pragma unroll
    for (int j = 0; j < 4; ++j) {
        _Float16 h = (_Float16)f1[j];
        H[4 + j] = h; L[4 + j] = (_Float16)((f1[j] - (float)h) * LOSCALE);
    }
}

// ---------------------------------------------------------------------------
// MoE router: async-DMA staged A + counted-vmcnt pipeline (T3/T4 pattern).
// 512 blocks x 4 waves; block = 32 tokens; waves split experts (16 each).
//
// R5 evidence: per-round __syncthreads drained vmcnt(0) every round ->
// loads in flight only a fraction of the time; all blocks convoy on HBM
// (7.9K cy/round vs ~1.5K of pipe work). Plus 5.27M LDS bank conflicts
// from the 528B-stride stage layout. This round:
//   - A staged via global_load_lds as raw f32 (no stager VALU, no VGPR
//     round-trip, exact 128B-segment tiling), triple-buffered; DMA for
//     round r+2 issued in round r.
//   - XOR swizzle col ^= (tok&7)<<4 applied on the DMA's GLOBAL source
//     (LDS dest stays linear, m104/m173) and on ds_read addresses ->
//     conflict-free per 8-lane phase; zero ds_writes in the loop.
//   - raw s_barrier + asm s_waitcnt vmcnt(12) (= this round's 4 DMA + 8 B
//     loads stay in flight across the barrier; never drain to 0 in-loop).
//   - f32->f16 hi/lo split done per-wave after the LDS read (VALU has room).
// ---------------------------------------------------------------------------
__global__ __launch_bounds__(256) void moe_kernel(const float* __restrict__ A,
                                                  const _Float16* __restrict__ Whi,
                                                  const _Float16* __restrict__ Wlo,
                                                  float* __restrict__ out_w,
                                                  float* __restrict__ out_i,
                                                  float* __restrict__ out_aux,
                                                  float* __restrict__ cnt_ws,
                                                  float* __restrict__ sp_ws,
                                                  unsigned int* __restrict__ ticket) {
    __shared__ float stage[NBUF][BUFSZ];        // 48 KB
    __shared__ float xch[TOKPB * LSTRIDE];      // 8.4 KB
    __shared__ float s_cnt[NEXP];
    __shared__ float s_sp[NEXP];
    __shared__ int   s_last;

    const int tid   = threadIdx.x;
    const int lane  = tid & 63;
    const int wv    = tid >> 6;          // expert tile 0..3 (uniform per wave)
    const int row16 = lane & 15;
    const int quad  = lane >> 4;
    const int tbase = blockIdx.x * TOKPB;

    if (tid < NEXP) { s_cnt[tid] = 0.f; s_sp[tid] = 0.f; }

    // ---- DMA source pointers: instr j writes LDS bytes (wv*4+j)*1024 + lane*16.
    // That slot holds (tok = (wv*4+j)*2 + (lane>>5), col byte = (lane&31)*16),
    // swizzled: source col = ((lane&31)*16) ^ ((tok&7)<<4).
    const float* asrc[4];
    #pragma unroll
    for (int j = 0; j < 4; ++j) {
        int tok  = (wv * 4 + j) * 2 + (lane >> 5);
        int colb = ((lane & 31) * 16) ^ ((tok & 7) << 4);
        asrc[j] = (const float*)((const char*)(A + (size_t)(tbase + tok) * DIM) + colb);
    }

    // ---- MFMA role: wave wv's 16 expert rows ----
    const _Float16* bhp = Whi + (size_t)(wv * 16 + row16) * DIM + quad * 8;
    const _Float16* blp = Wlo + (size_t)(wv * 16 + row16) * DIM + quad * 8;

    floatx4 acc0[2] = {};   // hi*hi         (mt = 0,1)
    floatx4 acc1[2] = {};   // hi*lo + lo*hi (carries 2^11)

    // reader swizzled column (in floats): (quad*8) ^ ((row16&7)*4); piece1 = ^4
    const int c0 = (quad * 8) ^ ((row16 & 7) * 4);

    // ---- prologue: DMA buf0 (round 0) + buf1 (round 1); preload B chunks 0-3 ----
    #pragma unroll
    for (int j = 0; j < 4; ++j) gl_lds16(asrc[j],       &stage[0][0], (wv * 4 + j) * 1024);
    #pragma unroll
    for (int j = 0; j < 4; ++j) gl_lds16(asrc[j] + 128, &stage[1][0], (wv * 4 + j) * 1024);

    half8 bh[4], bl[4];
    #pragma unroll
    for (int c = 0; c < 4; ++c) {
        bh[c] = *(const half8*)(bhp + c * 32);
        bl[c] = *(const half8*)(blp + c * 32);
    }
    // newest 12 in flight = DMA buf1 (4) + B (8); drains DMA buf0 only
    asm volatile("s_waitcnt vmcnt(12)" ::: "memory");
    __builtin_amdgcn_sched_barrier(0);
    __builtin_amdgcn_s_barrier();
    __builtin_amdgcn_sched_barrier(0);

    // ---- main loop: 16 rounds of 128 k ----
    #pragma unroll
    for (int r = 0; r < NROUNDS; ++r) {
        const float* rb = &stage[r % 3][0];

        if (r < NROUNDS - 2) {          // DMA round r+2 into buf[(r+2)%3]
            #pragma unroll
            for (int j = 0; j < 4; ++j)
                gl_lds16(asrc[j] + (r + 2) * 128, &stage[(r + 2) % 3][0], (wv * 4 + j) * 1024);
        }

        #pragma unroll
        for (int I = 0; I < 4; ++I) {
            const float* p0 = rb + row16 * 128 + I * 32;
            floatx4 f0 = *(const floatx4*)(p0 + c0);
            floatx4 f1 = *(const floatx4*)(p0 + (c0 ^ 4));
            half8 ah, al; split8(f0, f1, ah, al);
            acc0[0] = __builtin_amdgcn_mfma_f32_16x16x32_f16(ah, bh[I], acc0[0], 0, 0, 0);
            acc1[0] = __builtin_amdgcn_mfma_f32_16x16x32_f16(ah, bl[I], acc1[0], 0, 0, 0);
            acc1[0] = __builtin_amdgcn_mfma_f32_16x16x32_f16(al, bh[I], acc1[0], 0, 0, 0);

            const float* p1 = rb + (16 + row16) * 128 + I * 32;
            f0 = *(const floatx4*)(p1 + c0);
            f1 = *(const floatx4*)(p1 + (c0 ^ 4));
            split8(f0, f1, ah, al);
            acc0[1] = __builtin_amdgcn_mfma_f32_16x16x32_f16(ah, bh[I], acc0[1], 0, 0, 0);
            acc1[1] = __builtin_amdgcn_mfma_f32_16x16x32_f16(ah, bl[I], acc1[1], 0, 0, 0);
            acc1[1] = __builtin_amdgcn_mfma_f32_16x16x32_f16(al, bh[I], acc1[1], 0, 0, 0);

            if (r < NROUNDS - 1) {      // reload B for next round (after use)
                bh[I] = *(const half8*)(bhp + ((r + 1) * 4 + I) * 32);
                bl[I] = *(const half8*)(blp + ((r + 1) * 4 + I) * 32);
            }
        }

        // counted drain: keep this round's DMA(4)+B(8) in flight; ensure
        // the DMA for round r+1's buffer is complete before the barrier.
        if (r < NROUNDS - 2) {
            asm volatile("s_waitcnt vmcnt(12)" ::: "memory");
        } else if (r == NROUNDS - 2) {
            asm volatile("s_waitcnt vmcnt(8)" ::: "memory");
        }
        if (r < NROUNDS - 1) {
            __builtin_amdgcn_sched_barrier(0);
            __builtin_amdgcn_s_barrier();
            __builtin_amdgcn_sched_barrier(0);
        }
    }

    // ---- exchange: C layout col=lane&15 (expert sub), row=quad*4+reg ----
    const float inv = 1.0f / LOSCALE;
    #pragma unroll
    for (int mt = 0; mt < 2; ++mt)
        #pragma unroll
        for (int reg = 0; reg < 4; ++reg) {
            int tok = mt * 16 + quad * 4 + reg;
            xch[tok * LSTRIDE + wv * 16 + row16] = acc0[mt][reg] + acc1[mt][reg] * inv;
        }
    __syncthreads();

    // ---- epilogue: wave wv handles tokens [wv*8, wv*8+8); lane = expert ----
    float sp = 0.f, cnt = 0.f;
    for (int i = 0; i < 8; ++i) {
        int t = wv * 8 + i;
        float lg = xch[t * LSTRIDE + lane];

        float m = lg;
        #pragma unroll
        for (int off = 32; off; off >>= 1) m = fmaxf(m, __shfl_xor(m, off));
        float e = expf(lg - m);
        float ssum = e;
        #pragma unroll
        for (int off = 32; off; off >>= 1) ssum += __shfl_xor(ssum, off);
        float score = e / ssum;
        sp += score;

        int rank = 0;
        #pragma unroll
        for (int j = 0; j < 64; ++j) {
            float sj = __shfl(score, j);
            rank += (sj > score) || (sj == score && j < lane);
        }
        bool sel = rank < TOPK;

        float v = sel ? score : 0.f;
        #pragma unroll
        for (int off = 32; off; off >>= 1) v += __shfl_xor(v, off);

        if (sel) {
            out_w[(size_t)(tbase + t) * TOPK + rank] = score / v;
            out_i[(size_t)(tbase + t) * TOPK + rank] = (float)lane;
            cnt += 1.f;
        }
    }

    atomicAdd(&s_sp[lane], sp);
    atomicAdd(&s_cnt[lane], cnt);
    __syncthreads();
    const int rep = (blockIdx.x & (NREP - 1)) * NEXP;
    if (tid < 64)       atomicAdd(&cnt_ws[rep + tid], s_cnt[tid]);
    else if (tid < 128) atomicAdd(&sp_ws[rep + tid - 64], s_sp[tid - 64]);

    // release our atomics, then take a ticket; last block finalizes
    __threadfence();
    __syncthreads();
    if (tid == 0)
        s_last = (atomicAdd(ticket, 1u) == (unsigned)(gridDim.x - 1));
    __syncthreads();
    if (s_last && tid < 64) {
        float c = 0.f, p = 0.f;
        #pragma unroll
        for (int rr = 0; rr < NREP; ++rr) {
            c += atomicAdd(&cnt_ws[rr * NEXP + tid], 0.f);   // device-scope read
            p += atomicAdd(&sp_ws [rr * NEXP + tid], 0.f);
        }
        float v = (c / (float)(N_TOKENS * TOPK)) * (p / (float)N_TOKENS);
        #pragma unroll
        for (int off = 32; off; off >>= 1) v += __shfl_xor(v, off);
        if (tid == 0) out_aux[0] = 0.001f * (float)NEXP * v;
    }
}

extern "C" void kernel_launch(void* const* d_in, const int* in_sizes, int n_in,
                              void* d_out, int out_size, void* d_ws, size_t ws_size,
                              hipStream_t stream) {
    const float* A = (const float*)d_in[0];   // hidden_states (16384 x 2048)
    const float* W = (const float*)d_in[1];   // weight        (64 x 2048)
    float* out = (float*)d_out;

    _Float16*     whi    = (_Float16*)d_ws;
    _Float16*     wlo    = whi + (size_t)NEXP * DIM;
    float*        cnt_ws = (float*)(wlo + (size_t)NEXP * DIM);
    float*        sp_ws  = cnt_ws + (size_t)NREP * NEXP;
    unsigned int* ticket = (unsigned int*)(sp_ws + (size_t)NREP * NEXP);

    // zero cnt(8KB) + sp(8KB) + ticket(4B)
    hipMemsetAsync(cnt_ws, 0, 2 * NREP * NEXP * sizeof(float) + sizeof(unsigned int), stream);

    hipLaunchKernelGGL(wprep_kernel, dim3(NEXP * DIM / 256), dim3(256), 0, stream,
                       W, whi, wlo);

    float* out_w = out;
    float* out_i = out + (size_t)N_TOKENS * TOPK;
    float* out_a = out + 2 * (size_t)N_TOKENS * TOPK;

    hipLaunchKernelGGL(moe_kernel, dim3(NBLOCKS), dim3(256), 0, stream,
                       A, whi, wlo, out_w, out_i, out_a, cnt_ws, sp_ws, ticket);
}